// Round 16
// baseline (894.609 us; speedup 1.0000x reference)
//
#include <hip/hip_runtime.h>

// Problem constants
#define K_   4096
#define S0   67108864     // N*M*H*W*K
#define NP   16384        // N*M*H*W
#define NEG_INF_ (-1.0e9f)
#define LCB_STRIDE 36     // floats; 144 B rows (b128 reads: 2-way banks = free)

typedef float fx4 __attribute__((ext_vector_type(4)));  // NT-store-compatible

// --- tiny pre-kernel: code_usage -> expo, stored in ws[0] ---
__global__ __launch_bounds__(256) void usage_kernel(const float* __restrict__ freq,
                                                    float* __restrict__ ws) {
  __shared__ int sc[256];
  int c = 0;
  for (int i = threadIdx.x; i < 4 * K_; i += 256) c += (freq[i] > 1e-7f) ? 1 : 0;
  sc[threadIdx.x] = c;
  __syncthreads();
  for (int s = 128; s > 0; s >>= 1) {
    if (threadIdx.x < s) sc[threadIdx.x] += sc[threadIdx.x + s];
    __syncthreads();
  }
  if (threadIdx.x == 0) {
    float u = (float)sc[0] * (1.0f / 16384.0f);   // exact: count / 2^14
    u = fminf(fmaxf(u, 0.0f), 1.0f);
    ws[0] = 12.0f - 11.0f * (u * u);              // expo = BITS - (BITS-1)*u^2
  }
}

__device__ __forceinline__ void amax_comb(float& v, int& i, float v2, int i2) {
  // max with first-index (min idx) tie-break — associative & commutative
  if (v2 > v || (v2 == v && i2 < i)) { v = v2; i = i2; }
}

// R16 = R9 + T14 async-stage pipeline. Per kt: ds_write tile-kt from regs
// (counted vmcnt drains only cb4[kt]; FIFO leaves dn/gn in flight), raw
// lgkm-only barrier, THEN issue cb4[kt+1]+dn/gn[kt+1] so they are in flight
// across the whole compute phase; bare barrier2 (lgkm naturally 0) never
// drains vmcnt. dn/gn A/B-buffered via manual 2x unroll (no runtime idx).
// Numerics / tile layout / FMA order / tail byte-identical to R9.
#define MCQ_PHASE(KT, DN_C, GN_C, FV_C, DN_N, GN_N, FV_N)                     \
  {                                                                           \
    const int k = ((KT) << 8) + tid;                                          \
    _Pragma("unroll")                                                         \
    for (int it = 0; it < 8; ++it) {                                          \
      const int f = (it << 8) + tid;                                          \
      const int r = f >> 3, j = f & 7;                                        \
      *(float4*)&lcb[r * LCB_STRIDE + (j << 2)] = cbv[it];                    \
    }                                                                         \
    asm volatile("s_waitcnt lgkmcnt(0)" ::: "memory");                        \
    __builtin_amdgcn_sched_barrier(0);                                        \
    __builtin_amdgcn_s_barrier();                                             \
    __builtin_amdgcn_sched_barrier(0);                                        \
    if ((KT) < 15) {                                                          \
      _Pragma("unroll")                                                       \
      for (int it = 0; it < 8; ++it)                                          \
        cbv[it] = cb4[(((KT) + 1) << 11) + (it << 8) + tid];                  \
      const int kn = k + 256;                                                 \
      _Pragma("unroll")                                                       \
      for (int p = 0; p < 4; ++p) {                                           \
        const size_t offn = base0 + (size_t)p * K_ + kn;                      \
        DN_N[p] = __builtin_nontemporal_load(dn + offn);                      \
        GN_N[p] = __builtin_nontemporal_load(gn + offn);                      \
      }                                                                       \
      FV_N = freqm[kn];                                                       \
    }                                                                         \
    float dotv[4];                                                            \
    _Pragma("unroll")                                                         \
    for (int p = 0; p < 4; ++p) dotv[p] = 0.f;                                \
    float c2 = 0.f;                                                           \
    _Pragma("unroll")                                                         \
    for (int j = 0; j < 8; ++j) {                                             \
      const float4 c = *(const float4*)&lcb[tid * LCB_STRIDE + (j << 2)];     \
      c2 += c.x * c.x; c2 += c.y * c.y; c2 += c.z * c.z; c2 += c.w * c.w;     \
      _Pragma("unroll")                                                       \
      for (int p = 0; p < 4; ++p) {                                           \
        const float4 xq = *(const float4*)&xs[p][4 * j];                      \
        float a = dotv[p];                                                    \
        a = fmaf(c.x, xq.x, a);                                               \
        a = fmaf(c.y, xq.y, a);                                               \
        a = fmaf(c.z, xq.z, a);                                               \
        a = fmaf(c.w, xq.w, a);                                               \
        dotv[p] = a;                                                          \
      }                                                                       \
    }                                                                         \
    _Pragma("unroll")                                                         \
    for (int p = 0; p < 4; ++p) {                                             \
      const size_t off = base0 + (size_t)p * K_ + k;                          \
      const float dist = (x2r[p] + c2) - 2.0f * dotv[p];                      \
      float lg = dist * (-0.015625f) * tlb;                                   \
      const float pv = exp2f(expo * log2f(DN_C[p]));                          \
      if (pv < FV_C) lg = lg + NEG_INF_;                                      \
      __builtin_nontemporal_store(lg, out_logit + off);                       \
      if (lg > lval[p]) { lval[p] = lg; lidx[p] = k; }                        \
      const float lgg = lg + GN_C[p];                                         \
      if (lgg > gval[p]) { gval[p] = lgg; gidx[p] = k; }                      \
    }                                                                         \
    __builtin_amdgcn_sched_barrier(0);                                        \
    __builtin_amdgcn_s_barrier();                                             \
    __builtin_amdgcn_sched_barrier(0);                                        \
  }

__global__ __launch_bounds__(256, 1) void mcq_kernel(
    const float* __restrict__ x,    // (N, M*D, H, W)
    const float* __restrict__ cb,   // (M, K, D)
    const float* __restrict__ freq, // (M, K)
    const float* __restrict__ temp, // (M)
    const float* __restrict__ dn,   // (N, M, H, W, K)
    const float* __restrict__ gn,   // (N, M, H, W, K)
    const float* __restrict__ ws,
    float* __restrict__ out)
{
  const int tid   = threadIdx.x;
  const int nm    = blockIdx.x >> 8;   // 0..15  (n*M+m)
  const int ptile = blockIdx.x & 255;  // 0..255
  const int m     = nm & 3;
  const int hw0   = ptile << 2;        // 4 positions
  const int rowbase = (nm << 10) + hw0;

  __shared__ float xs[4][32];
  __shared__ float x2s[4];
  __shared__ float lcb[256 * LCB_STRIDE];   // 36 KB staged codebook tile
  if (tid < 128) {
    const int d = tid >> 2, p = tid & 3;
    xs[p][d] = x[((size_t)(nm >> 2) * 128 + (size_t)m * 32 + d) * 1024 + hw0 + p];
  }
  __syncthreads();
  if (tid < 4) {
    float s = 0.f;
    #pragma unroll
    for (int d = 0; d < 32; ++d) s += xs[tid][d] * xs[tid][d];
    x2s[tid] = s;
  }
  __syncthreads();

  const float expo = ws[0];
  const float tlb  = fmaxf(temp[m], 1e-7f);  // lower_bound fwd
  const float* __restrict__ cbm   = cb + (size_t)m * K_ * 32;
  const float4* __restrict__ cb4  = (const float4*)cbm;
  const float* __restrict__ freqm = freq + m * K_;
  float* __restrict__ out_sample = out;
  float* __restrict__ out_code   = out + S0;
  float* __restrict__ out_onehot = out + S0 + NP;
  float* __restrict__ out_logit  = out + (size_t)2 * S0 + NP;

  float x2r[4];
  #pragma unroll
  for (int p = 0; p < 4; ++p) x2r[p] = x2s[p];

  float lval[4], gval[4];
  int   lidx[4], gidx[4];
  #pragma unroll
  for (int p = 0; p < 4; ++p) {
    lval[p] = -3.402823466e38f; gval[p] = -3.402823466e38f;
    lidx[p] = 0; gidx[p] = 0;
  }

  const size_t base0 = (size_t)rowbase * K_;

  // pipeline prologue: tile kt=0 into cbv regs, dn/gn kt=0 into A buffers
  float4 cbv[8];
  #pragma unroll
  for (int it = 0; it < 8; ++it) cbv[it] = cb4[(it << 8) + tid];
  float dnvA[4], gnvA[4], dnvB[4], gnvB[4], fvA, fvB;
  #pragma unroll
  for (int p = 0; p < 4; ++p) {
    const size_t off = base0 + (size_t)p * K_ + tid;
    dnvA[p] = __builtin_nontemporal_load(dn + off);
    gnvA[p] = __builtin_nontemporal_load(gn + off);
  }
  fvA = freqm[tid];
  fvB = 0.f;

  for (int kt2 = 0; kt2 < 16; kt2 += 2) {
    MCQ_PHASE(kt2,     dnvA, gnvA, fvA, dnvB, gnvB, fvB)
    MCQ_PHASE(kt2 + 1, dnvB, gnvB, fvB, dnvA, gnvA, fvA)
  }

  // cross-thread argmax reduction: per-wave butterfly, then 4 partials via LDS
  __shared__ float rv[4][8];
  __shared__ int   ri[4][8];
  __shared__ int   widx[2][4];   // [0]=logit winner (one_hot), [1]=gumbel winner (sample)
  const int wave = tid >> 6, lane = tid & 63;
  #pragma unroll
  for (int p = 0; p < 4; ++p) {
    float v = lval[p]; int i = lidx[p];
    #pragma unroll
    for (int s = 1; s < 64; s <<= 1) {
      float v2 = __shfl_xor(v, s, 64);
      int   i2 = __shfl_xor(i, s, 64);
      amax_comb(v, i, v2, i2);
    }
    if (lane == 0) { rv[wave][p*2] = v; ri[wave][p*2] = i; }
    v = gval[p]; i = gidx[p];
    #pragma unroll
    for (int s = 1; s < 64; s <<= 1) {
      float v2 = __shfl_xor(v, s, 64);
      int   i2 = __shfl_xor(i, s, 64);
      amax_comb(v, i, v2, i2);
    }
    if (lane == 0) { rv[wave][p*2+1] = v; ri[wave][p*2+1] = i; }
  }
  __syncthreads();
  if (tid < 8) {
    float v = rv[0][tid]; int i = ri[0][tid];
    amax_comb(v, i, rv[1][tid], ri[1][tid]);
    amax_comb(v, i, rv[2][tid], ri[2][tid]);
    amax_comb(v, i, rv[3][tid], ri[3][tid]);
    const int p   = tid >> 1;
    const int sel = tid & 1;
    widx[sel][p] = i;
    if (sel == 0) out_code[rowbase + p] = (float)i;   // argmax(logit) -> code
  }
  __syncthreads();

  // tail: write full one-hot rows for sample and one_hot (coalesced NT fx4)
  #pragma unroll
  for (int p = 0; p < 4; ++p) {
    const size_t rowoff = base0 + (size_t)p * K_;
    const int wl = widx[0][p];   // one_hot winner  (argmax logit)
    const int wg = widx[1][p];   // sample winner   (argmax logit+gumbel)
    #pragma unroll
    for (int j = 0; j < 4; ++j) {
      const int k0 = (j << 10) + (tid << 2);
      fx4 vo, vs;
      vo.x = (k0 + 0 == wl) ? 1.0f : 0.0f;
      vo.y = (k0 + 1 == wl) ? 1.0f : 0.0f;
      vo.z = (k0 + 2 == wl) ? 1.0f : 0.0f;
      vo.w = (k0 + 3 == wl) ? 1.0f : 0.0f;
      vs.x = (k0 + 0 == wg) ? 1.0f : 0.0f;
      vs.y = (k0 + 1 == wg) ? 1.0f : 0.0f;
      vs.z = (k0 + 2 == wg) ? 1.0f : 0.0f;
      vs.w = (k0 + 3 == wg) ? 1.0f : 0.0f;
      __builtin_nontemporal_store(vo, (fx4*)(out_onehot + rowoff + k0));
      __builtin_nontemporal_store(vs, (fx4*)(out_sample + rowoff + k0));
    }
  }
}

extern "C" void kernel_launch(void* const* d_in, const int* in_sizes, int n_in,
                              void* d_out, int out_size, void* d_ws, size_t ws_size,
                              hipStream_t stream) {
  const float* x    = (const float*)d_in[0];
  const float* cb   = (const float*)d_in[1];
  const float* freq = (const float*)d_in[2];
  const float* temp = (const float*)d_in[3];
  const float* dn   = (const float*)d_in[4];
  const float* gn   = (const float*)d_in[5];
  float* out = (float*)d_out;
  float* ws  = (float*)d_ws;

  // no memset needed: kernel writes every element of all four outputs
  usage_kernel<<<1, 256, 0, stream>>>(freq, ws);
  mcq_kernel<<<4096, 256, 0, stream>>>(x, cb, freq, temp, dn, gn, ws, out);
}

// Round 17
// 325.885 us; speedup vs baseline: 2.7452x; 2.7452x over previous
//
#include <hip/hip_runtime.h>

// Problem constants
#define K_   4096
#define S0   67108864     // N*M*H*W*K
#define NP   16384        // N*M*H*W
#define NEG_INF_ (-1.0e9f)
#define LCB_STRIDE 36     // floats; 144 B rows: 16-B aligned, spread banks

typedef float fx4 __attribute__((ext_vector_type(4)));  // NT-store-compatible

// --- tiny pre-kernel: code_usage -> expo, stored in ws[0] ---
__global__ __launch_bounds__(256) void usage_kernel(const float* __restrict__ freq,
                                                    float* __restrict__ ws) {
  __shared__ int sc[256];
  int c = 0;
  for (int i = threadIdx.x; i < 4 * K_; i += 256) c += (freq[i] > 1e-7f) ? 1 : 0;
  sc[threadIdx.x] = c;
  __syncthreads();
  for (int s = 128; s > 0; s >>= 1) {
    if (threadIdx.x < s) sc[threadIdx.x] += sc[threadIdx.x + s];
    __syncthreads();
  }
  if (threadIdx.x == 0) {
    float u = (float)sc[0] * (1.0f / 16384.0f);   // exact: count / 2^14
    u = fminf(fmaxf(u, 0.0f), 1.0f);
    ws[0] = 12.0f - 11.0f * (u * u);              // expo = BITS - (BITS-1)*u^2
  }
}

__device__ __forceinline__ void amax_comb(float& v, int& i, float v2, int i2) {
  // max with first-index (min idx) tie-break — associative & commutative
  if (v2 > v || (v2 == v && i2 < i)) { v = v2; i = i2; }
}

// FINAL = R9 (best of 16 rounds: 326.6 us total). TP=4 positions/block,
// 36 KB coalesced LDS codebook tile (fixes the uncoalesced per-lane
// codebook reads diagnosed in R8), cap-128 registers (spill-free), fused
// pure-write one-hot tail (no memset dispatch). Six structural variants
// (occupancy, LDS-op count, raw barriers, register caching, phase-split,
// async pipeline) all measured flat-or-worse; this is the basin floor.
__global__ __launch_bounds__(256, 2) void mcq_kernel(
    const float* __restrict__ x,    // (N, M*D, H, W)
    const float* __restrict__ cb,   // (M, K, D)
    const float* __restrict__ freq, // (M, K)
    const float* __restrict__ temp, // (M)
    const float* __restrict__ dn,   // (N, M, H, W, K)
    const float* __restrict__ gn,   // (N, M, H, W, K)
    const float* __restrict__ ws,
    float* __restrict__ out)
{
  const int tid   = threadIdx.x;
  const int nm    = blockIdx.x >> 8;   // 0..15  (n*M+m)
  const int ptile = blockIdx.x & 255;  // 0..255
  const int m     = nm & 3;
  const int hw0   = ptile << 2;        // 4 positions
  const int rowbase = (nm << 10) + hw0;

  __shared__ float xs[4][32];
  __shared__ float x2s[4];
  __shared__ float lcb[256 * LCB_STRIDE];   // 36 KB staged codebook tile
  if (tid < 128) {
    const int d = tid >> 2, p = tid & 3;
    xs[p][d] = x[((size_t)(nm >> 2) * 128 + (size_t)m * 32 + d) * 1024 + hw0 + p];
  }
  __syncthreads();
  if (tid < 4) {
    float s = 0.f;
    #pragma unroll
    for (int d = 0; d < 32; ++d) s += xs[tid][d] * xs[tid][d];
    x2s[tid] = s;
  }
  __syncthreads();

  const float expo = ws[0];
  const float tlb  = fmaxf(temp[m], 1e-7f);  // lower_bound fwd
  const float* __restrict__ cbm   = cb + (size_t)m * K_ * 32;
  const float4* __restrict__ cb4  = (const float4*)cbm;
  const float* __restrict__ freqm = freq + m * K_;
  float* __restrict__ out_sample = out;
  float* __restrict__ out_code   = out + S0;
  float* __restrict__ out_onehot = out + S0 + NP;
  float* __restrict__ out_logit  = out + (size_t)2 * S0 + NP;

  float x2r[4];
  #pragma unroll
  for (int p = 0; p < 4; ++p) x2r[p] = x2s[p];

  float lval[4], gval[4];
  int   lidx[4], gidx[4];
  #pragma unroll
  for (int p = 0; p < 4; ++p) {
    lval[p] = -3.402823466e38f; gval[p] = -3.402823466e38f;
    lidx[p] = 0; gidx[p] = 0;
  }

  const size_t base0 = (size_t)rowbase * K_;

  for (int kt = 0; kt < 16; ++kt) {
    const int k = (kt << 8) + tid;
    // 1) batch-issue streaming loads (latency overlaps the LDS fill below)
    float dnv[4], gnv[4];
    #pragma unroll
    for (int p = 0; p < 4; ++p) {
      const size_t off = base0 + (size_t)p * K_ + k;
      dnv[p] = __builtin_nontemporal_load(dn + off);
      gnv[p] = __builtin_nontemporal_load(gn + off);
    }
    const float fv = freqm[k];
    // 2) cooperative COALESCED tile load: tile is contiguous (cb4[kt*2048+f])
    #pragma unroll
    for (int it = 0; it < 8; ++it) {
      const int f = (it << 8) + tid;            // 0..2047
      const float4 v = cb4[(kt << 11) + f];
      const int r = f >> 3, j = f & 7;
      *(float4*)&lcb[r * LCB_STRIDE + (j << 2)] = v;
    }
    __syncthreads();
    // 3) per-thread row dot from LDS — proven FMA order
    float dotv[4];
    #pragma unroll
    for (int p = 0; p < 4; ++p) dotv[p] = 0.f;
    float c2 = 0.f;
    #pragma unroll
    for (int j = 0; j < 8; ++j) {
      const float4 c = *(const float4*)&lcb[tid * LCB_STRIDE + (j << 2)];
      c2 += c.x * c.x; c2 += c.y * c.y; c2 += c.z * c.z; c2 += c.w * c.w;
      #pragma unroll
      for (int p = 0; p < 4; ++p) {
        const float4 xq = *(const float4*)&xs[p][4 * j];
        float a = dotv[p];
        a = fmaf(c.x, xq.x, a);
        a = fmaf(c.y, xq.y, a);
        a = fmaf(c.z, xq.z, a);
        a = fmaf(c.w, xq.w, a);
        dotv[p] = a;
      }
    }
    // 4) logit + mask + argmax updates
    #pragma unroll
    for (int p = 0; p < 4; ++p) {
      const size_t off = base0 + (size_t)p * K_ + k;
      const float dist = (x2r[p] + c2) - 2.0f * dotv[p];
      float lg = dist * (-0.015625f) * tlb;   // (-dist/64)*tlb
      const float pv = exp2f(expo * log2f(dnv[p]));
      if (pv < fv) lg = lg + NEG_INF_;
      __builtin_nontemporal_store(lg, out_logit + off);
      if (lg > lval[p]) { lval[p] = lg; lidx[p] = k; }
      const float lgg = lg + gnv[p];
      if (lgg > gval[p]) { gval[p] = lgg; gidx[p] = k; }
    }
    __syncthreads();   // lcb reused next kt
  }

  // cross-thread argmax reduction: per-wave butterfly, then 4 partials via LDS
  __shared__ float rv[4][8];
  __shared__ int   ri[4][8];
  __shared__ int   widx[2][4];   // [0]=logit winner (one_hot), [1]=gumbel winner (sample)
  const int wave = tid >> 6, lane = tid & 63;
  #pragma unroll
  for (int p = 0; p < 4; ++p) {
    float v = lval[p]; int i = lidx[p];
    #pragma unroll
    for (int s = 1; s < 64; s <<= 1) {
      float v2 = __shfl_xor(v, s, 64);
      int   i2 = __shfl_xor(i, s, 64);
      amax_comb(v, i, v2, i2);
    }
    if (lane == 0) { rv[wave][p*2] = v; ri[wave][p*2] = i; }
    v = gval[p]; i = gidx[p];
    #pragma unroll
    for (int s = 1; s < 64; s <<= 1) {
      float v2 = __shfl_xor(v, s, 64);
      int   i2 = __shfl_xor(i, s, 64);
      amax_comb(v, i, v2, i2);
    }
    if (lane == 0) { rv[wave][p*2+1] = v; ri[wave][p*2+1] = i; }
  }
  __syncthreads();
  if (tid < 8) {
    float v = rv[0][tid]; int i = ri[0][tid];
    amax_comb(v, i, rv[1][tid], ri[1][tid]);
    amax_comb(v, i, rv[2][tid], ri[2][tid]);
    amax_comb(v, i, rv[3][tid], ri[3][tid]);
    const int p   = tid >> 1;
    const int sel = tid & 1;
    widx[sel][p] = i;
    if (sel == 0) out_code[rowbase + p] = (float)i;   // argmax(logit) -> code
  }
  __syncthreads();

  // tail: write full one-hot rows for sample and one_hot (coalesced NT fx4)
  #pragma unroll
  for (int p = 0; p < 4; ++p) {
    const size_t rowoff = base0 + (size_t)p * K_;
    const int wl = widx[0][p];   // one_hot winner  (argmax logit)
    const int wg = widx[1][p];   // sample winner   (argmax logit+gumbel)
    #pragma unroll
    for (int j = 0; j < 4; ++j) {
      const int k0 = (j << 10) + (tid << 2);
      fx4 vo, vs;
      vo.x = (k0 + 0 == wl) ? 1.0f : 0.0f;
      vo.y = (k0 + 1 == wl) ? 1.0f : 0.0f;
      vo.z = (k0 + 2 == wl) ? 1.0f : 0.0f;
      vo.w = (k0 + 3 == wl) ? 1.0f : 0.0f;
      vs.x = (k0 + 0 == wg) ? 1.0f : 0.0f;
      vs.y = (k0 + 1 == wg) ? 1.0f : 0.0f;
      vs.z = (k0 + 2 == wg) ? 1.0f : 0.0f;
      vs.w = (k0 + 3 == wg) ? 1.0f : 0.0f;
      __builtin_nontemporal_store(vo, (fx4*)(out_onehot + rowoff + k0));
      __builtin_nontemporal_store(vs, (fx4*)(out_sample + rowoff + k0));
    }
  }
}

extern "C" void kernel_launch(void* const* d_in, const int* in_sizes, int n_in,
                              void* d_out, int out_size, void* d_ws, size_t ws_size,
                              hipStream_t stream) {
  const float* x    = (const float*)d_in[0];
  const float* cb   = (const float*)d_in[1];
  const float* freq = (const float*)d_in[2];
  const float* temp = (const float*)d_in[3];
  const float* dn   = (const float*)d_in[4];
  const float* gn   = (const float*)d_in[5];
  float* out = (float*)d_out;
  float* ws  = (float*)d_ws;

  // no memset needed: kernel writes every element of all four outputs
  usage_kernel<<<1, 256, 0, stream>>>(freq, ws);
  mcq_kernel<<<4096, 256, 0, stream>>>(x, cb, freq, temp, dn, gn, ws, out);
}